// Round 15
// baseline (1082.574 us; speedup 1.0000x reference)
//
#include <hip/hip_runtime.h>

#define NN 1024
#define KK 128

typedef __attribute__((ext_vector_type(8))) short bf16x8;
typedef __attribute__((ext_vector_type(4))) float f32x4;
typedef __attribute__((ext_vector_type(8))) unsigned short u16x8;

__device__ __forceinline__ unsigned int bf16rne(float x) {
    unsigned int u = __float_as_uint(x);
    return (u + 0x7FFFu + ((u >> 16) & 1u)) >> 16;
}

__device__ __forceinline__ void split8(const float* xs, bf16x8& h8, bf16x8& l8) {
    #pragma unroll
    for (int j = 0; j < 8; ++j) {
        unsigned int hb = bf16rne(xs[j]);
        float hf = __uint_as_float(hb << 16);
        h8[j] = (short)hb;
        l8[j] = (short)bf16rne(xs[j] - hf);
    }
}

// ---------------------------------------------------------------------------
// MFMA sandwich, split-bf16, 512 threads / 8 waves (R12 form: pan staging).
// ---------------------------------------------------------------------------
template<bool FINAL>
__global__ __launch_bounds__(512) void sandwich_mfma(
    const float* __restrict__ A_, const float* __restrict__ B_,
    float* __restrict__ Out,
    const float* __restrict__ Lp, const float* __restrict__ Lq,
    const float* __restrict__ obs, const float* __restrict__ beta)
{
    __shared__ short lds_buf[69632];
    short* Bth = lds_buf;
    short* Btl = lds_buf + 17408;
    short* Tth = lds_buf + 34816;
    short* Ttl = lds_buf + 52224;
    float* pan = (float*)(lds_buf + 34816);
    __shared__ float wred[8];
    __shared__ float cs_sh;

    const int n    = blockIdx.x;
    const int tid  = threadIdx.x;
    const int lane = tid & 63;
    const int wid  = tid >> 6;
    const int wr   = wid >> 1;          // 0..3 row group (32 rows)
    const int wc   = wid & 1;           // 0..1 col group (64 cols)
    const int lm   = lane & 15;
    const int lk   = lane >> 4;
    const size_t base = (size_t)n * (KK * KK);

    if (FINAL) {
        float s = 0.f;
        for (int j = tid; j < NN; j += 512)
            if (j != n) s += beta[(size_t)j * NN + n];
        #pragma unroll
        for (int off = 32; off >= 1; off >>= 1) s += __shfl_down(s, off);
        if (lane == 0) wred[wid] = s;
        __syncthreads();
        if (tid == 0) {
            float t = 0.f;
            #pragma unroll
            for (int w = 0; w < 8; ++w) t += wred[w];
            cs_sh = t;
        }
    }

    // ---- stage Bt = B^T (hi/lo bf16) via two 64-col f32 panels ----
    #pragma unroll
    for (int cp = 0; cp < 2; ++cp) {
        #pragma unroll
        for (int it = 0; it < 4; ++it) {
            int gid = it * 512 + tid;
            int k   = gid >> 4;
            int c4  = (gid & 15) * 4;
            *(float4*)&pan[k * 66 + c4] =
                *(const float4*)(B_ + base + (size_t)k * KK + cp * 64 + c4);
        }
        __syncthreads();
        #pragma unroll
        for (int it = 0; it < 2; ++it) {
            int t  = it * 512 + tid;
            int c  = t >> 4;
            int ko = (t & 15) * 8;
            float xs[8];
            #pragma unroll
            for (int j = 0; j < 8; ++j) xs[j] = pan[(ko + j) * 66 + c];
            bf16x8 h8, l8;
            split8(xs, h8, l8);
            const int gc = cp * 64 + c;
            *(bf16x8*)&Bth[gc * 136 + ko] = h8;
            *(bf16x8*)&Btl[gc * 136 + ko] = l8;
        }
        __syncthreads();
    }

    // ================= stage 1: T = A @ B =================
    f32x4 acc[2][4];
    #pragma unroll
    for (int a = 0; a < 2; ++a)
        #pragma unroll
        for (int b = 0; b < 4; ++b) acc[a][b] = (f32x4){0.f, 0.f, 0.f, 0.f};

    #pragma unroll 1
    for (int ks = 0; ks < 4; ++ks) {
        const int k0 = ks * 32;
        bf16x8 afh[2], afl[2], bfh[4], bfl[4];
        #pragma unroll
        for (int rt = 0; rt < 2; ++rt) {
            const int r = wr * 32 + rt * 16 + lm;
            const float* ap = A_ + base + (size_t)r * KK + k0 + lk * 8;
            float4 x0 = *(const float4*)ap;
            float4 x1 = *(const float4*)(ap + 4);
            float xs[8] = {x0.x, x0.y, x0.z, x0.w, x1.x, x1.y, x1.z, x1.w};
            split8(xs, afh[rt], afl[rt]);
        }
        #pragma unroll
        for (int ct = 0; ct < 4; ++ct) {
            const int c = wc * 64 + ct * 16 + lm;
            bfh[ct] = *(const bf16x8*)&Bth[c * 136 + k0 + lk * 8];
            bfl[ct] = *(const bf16x8*)&Btl[c * 136 + k0 + lk * 8];
        }
        #pragma unroll
        for (int rt = 0; rt < 2; ++rt)
            #pragma unroll
            for (int ct = 0; ct < 4; ++ct) {
                acc[rt][ct] = __builtin_amdgcn_mfma_f32_16x16x32_bf16(
                    afh[rt], bfh[ct], acc[rt][ct], 0, 0, 0);
                acc[rt][ct] = __builtin_amdgcn_mfma_f32_16x16x32_bf16(
                    afh[rt], bfl[ct], acc[rt][ct], 0, 0, 0);
                acc[rt][ct] = __builtin_amdgcn_mfma_f32_16x16x32_bf16(
                    afl[rt], bfh[ct], acc[rt][ct], 0, 0, 0);
            }
    }

    // ---- T -> Tt[c][k] hi/lo ----
    #pragma unroll
    for (int rt = 0; rt < 2; ++rt)
        #pragma unroll
        for (int ct = 0; ct < 4; ++ct) {
            const int col  = wc * 64 + ct * 16 + lm;
            const int row0 = wr * 32 + rt * 16 + lk * 4;
            unsigned short h[4], l[4];
            #pragma unroll
            for (int j = 0; j < 4; ++j) {
                float x = acc[rt][ct][j];
                unsigned int hb = bf16rne(x);
                h[j] = (unsigned short)hb;
                l[j] = (unsigned short)bf16rne(x - __uint_as_float(hb << 16));
            }
            *(ushort4*)&Tth[col * 136 + row0] = make_ushort4(h[0], h[1], h[2], h[3]);
            *(ushort4*)&Ttl[col * 136 + row0] = make_ushort4(l[0], l[1], l[2], l[3]);
        }
    __syncthreads();

    // ================= stage 2: Out = B^T @ T =================
    f32x4 acc2[2][4];
    #pragma unroll
    for (int a = 0; a < 2; ++a)
        #pragma unroll
        for (int b = 0; b < 4; ++b) acc2[a][b] = (f32x4){0.f, 0.f, 0.f, 0.f};

    #pragma unroll 1
    for (int ks = 0; ks < 4; ++ks) {
        const int k0 = ks * 32;
        bf16x8 afh[2], afl[2], bfh[4], bfl[4];
        #pragma unroll
        for (int rt = 0; rt < 2; ++rt) {
            const int r = wr * 32 + rt * 16 + lm;
            afh[rt] = *(const bf16x8*)&Bth[r * 136 + k0 + lk * 8];
            afl[rt] = *(const bf16x8*)&Btl[r * 136 + k0 + lk * 8];
        }
        #pragma unroll
        for (int ct = 0; ct < 4; ++ct) {
            const int c = wc * 64 + ct * 16 + lm;
            bfh[ct] = *(const bf16x8*)&Tth[c * 136 + k0 + lk * 8];
            bfl[ct] = *(const bf16x8*)&Ttl[c * 136 + k0 + lk * 8];
        }
        #pragma unroll
        for (int rt = 0; rt < 2; ++rt)
            #pragma unroll
            for (int ct = 0; ct < 4; ++ct) {
                acc2[rt][ct] = __builtin_amdgcn_mfma_f32_16x16x32_bf16(
                    afh[rt], bfh[ct], acc2[rt][ct], 0, 0, 0);
                acc2[rt][ct] = __builtin_amdgcn_mfma_f32_16x16x32_bf16(
                    afh[rt], bfl[ct], acc2[rt][ct], 0, 0, 0);
                acc2[rt][ct] = __builtin_amdgcn_mfma_f32_16x16x32_bf16(
                    afl[rt], bfh[ct], acc2[rt][ct], 0, 0, 0);
            }
    }

    // ================= epilogue + store =================
    const float csv = FINAL ? cs_sh : 0.f;
    #pragma unroll
    for (int rt = 0; rt < 2; ++rt)
        #pragma unroll
        for (int ct = 0; ct < 4; ++ct) {
            const int col  = wc * 64 + ct * 16 + lm;
            const int row0 = wr * 32 + rt * 16 + lk * 4;
            #pragma unroll
            for (int j = 0; j < 4; ++j) {
                const int row = row0 + j;
                float o = acc2[rt][ct][j];
                if (FINAL) {
                    o += Lp[base + (size_t)row * KK + col]
                       + csv * Lq[base + (size_t)row * KK + col]
                       + obs[(size_t)row * KK + col];
                }
                Out[base + (size_t)row * KK + col] = o;
            }
        }
}

// ---------------------------------------------------------------------------
// Split-transpose: S (f32, [1024][16384]) -> Sth/Stl (bf16, [16384][1024]).
// ---------------------------------------------------------------------------
__global__ __launch_bounds__(256) void split_transpose_kernel(
    const float* __restrict__ S,
    unsigned short* __restrict__ Th, unsigned short* __restrict__ Tl)
{
    __shared__ float tile[128][132];
    const int tid = threadIdx.x;
    const int c0  = blockIdx.x * 128;
    const int k0  = blockIdx.y * 128;

    #pragma unroll
    for (int it = 0; it < 16; ++it) {
        int gid = it * 256 + tid;
        int kk  = gid >> 5;
        int c4  = (gid & 31) * 4;
        float4 v = *(const float4*)(S + (size_t)(k0 + kk) * 16384 + c0 + c4);
        *(float4*)&tile[kk][c4] = v;
    }
    __syncthreads();
    #pragma unroll
    for (int it = 0; it < 8; ++it) {
        int gid = it * 256 + tid;
        int c   = gid >> 4;
        int kc  = (gid & 15) * 8;
        u16x8 h, l;
        #pragma unroll
        for (int j = 0; j < 8; ++j) {
            float x = tile[kc + j][c];
            unsigned int hb = bf16rne(x);
            float hf = __uint_as_float(hb << 16);
            h[j] = (unsigned short)hb;
            l[j] = (unsigned short)bf16rne(x - hf);
        }
        size_t o = (size_t)(c0 + c) * 1024 + k0 + kc;
        *(u16x8*)(Th + o) = h;
        *(u16x8*)(Tl + o) = l;
    }
}

// ---------------------------------------------------------------------------
// GEMM body, 512 threads (8 waves, wave tile 32x64), on-the-fly beta split.
// Per-output MFMA chains identical to the 256-thread version => bit-identical.
// LDS need: 4 * 128*44 shorts = 45056 B (views into smem).
// ---------------------------------------------------------------------------
__device__ __forceinline__ void gemm_body(
    const float* __restrict__ beta,
    const unsigned short* __restrict__ Sth,
    const unsigned short* __restrict__ Stl,
    float* __restrict__ W,
    int cb_blk, int ib_blk, int tid, char* smem)
{
    unsigned short* Ah = (unsigned short*)smem;     // [128][44]
    unsigned short* Al = Ah + 128 * 44;
    unsigned short* Bh = Al + 128 * 44;
    unsigned short* Bl = Bh + 128 * 44;

    const int lane = tid & 63;
    const int wid  = tid >> 6;
    const int wr   = wid >> 1;       // 0..3
    const int wc   = wid & 1;        // 0..1
    const int lm   = lane & 15;
    const int lk   = lane >> 4;
    const int i0   = ib_blk * 128;
    const int cbase = cb_blk * 128;

    f32x4 acc[2][4];
    #pragma unroll
    for (int a = 0; a < 2; ++a)
        #pragma unroll
        for (int b = 0; b < 4; ++b) acc[a][b] = (f32x4){0.f, 0.f, 0.f, 0.f};

    const int ar = tid >> 2;            // 0..127
    const int akc = (tid & 3) * 8;      // 0..24

    for (int k0 = 0; k0 < 1024; k0 += 32) {
        // ---- A: beta[i0+ar][k0+akc..+8], split on the fly, zero diag ----
        {
            const int gi = i0 + ar;
            const float* bp = beta + (size_t)gi * NN + k0 + akc;
            float4 v0 = *(const float4*)bp;
            float4 v1 = *(const float4*)(bp + 4);
            float xs[8] = {v0.x, v0.y, v0.z, v0.w, v1.x, v1.y, v1.z, v1.w};
            #pragma unroll
            for (int e = 0; e < 8; ++e)
                if (gi == k0 + akc + e) xs[e] = 0.f;
            bf16x8 h8, l8;
            split8(xs, h8, l8);
            *(bf16x8*)&Ah[ar * 44 + akc] = h8;
            *(bf16x8*)&Al[ar * 44 + akc] = l8;
        }
        // ---- B: Sth/Stl[cbase+c][k0+kc..+8] ----
        {
            size_t o = (size_t)(cbase + ar) * 1024 + k0 + akc;
            *(u16x8*)&Bh[ar * 44 + akc] = *(const u16x8*)(Sth + o);
            *(u16x8*)&Bl[ar * 44 + akc] = *(const u16x8*)(Stl + o);
        }
        __syncthreads();

        bf16x8 afh[2], afl[2], bfh[4], bfl[4];
        #pragma unroll
        for (int rt = 0; rt < 2; ++rt) {
            const int r = wr * 32 + rt * 16 + lm;
            afh[rt] = *(const bf16x8*)&Ah[r * 44 + lk * 8];
            afl[rt] = *(const bf16x8*)&Al[r * 44 + lk * 8];
        }
        #pragma unroll
        for (int ct = 0; ct < 4; ++ct) {
            const int c = wc * 64 + ct * 16 + lm;
            bfh[ct] = *(const bf16x8*)&Bh[c * 44 + lk * 8];
            bfl[ct] = *(const bf16x8*)&Bl[c * 44 + lk * 8];
        }
        #pragma unroll
        for (int rt = 0; rt < 2; ++rt)
            #pragma unroll
            for (int ct = 0; ct < 4; ++ct) {
                acc[rt][ct] = __builtin_amdgcn_mfma_f32_16x16x32_bf16(
                    afh[rt], bfh[ct], acc[rt][ct], 0, 0, 0);
                acc[rt][ct] = __builtin_amdgcn_mfma_f32_16x16x32_bf16(
                    afh[rt], bfl[ct], acc[rt][ct], 0, 0, 0);
                acc[rt][ct] = __builtin_amdgcn_mfma_f32_16x16x32_bf16(
                    afl[rt], bfh[ct], acc[rt][ct], 0, 0, 0);
            }
        __syncthreads();
    }

    #pragma unroll
    for (int rt = 0; rt < 2; ++rt)
        #pragma unroll
        for (int ct = 0; ct < 4; ++ct) {
            const int col = cbase + wc * 64 + ct * 16 + lm;
            #pragma unroll
            for (int j = 0; j < 4; ++j) {
                const int row = i0 + wr * 32 + rt * 16 + lk * 4 + j;
                W[(size_t)row * 16384 + col] = acc[rt][ct][j];
            }
        }
}

// ---------------------------------------------------------------------------
// Invert body — R12 blocked GJ, NB=4, no pivot; 512 threads, 4x8 tile/thread.
// LDS need: (1056+1056+1024) floats = 12544 B (views into smem).
// ---------------------------------------------------------------------------
__device__ __forceinline__ void invert_body(
    const float* __restrict__ Om, float* __restrict__ Inv,
    int n, int tid, char* smem)
{
    float* rowblk  = (float*)smem;       // [2][4][132]
    float* rowstar = rowblk + 1056;      // [2][4][132]
    float* cpan    = rowstar + 1056;     // [2][128][4]

    const int rg  = tid >> 4;
    const int cg  = tid & 15;
    const int r0  = rg * 4;
    const int c0  = cg * 8;
    const size_t base = (size_t)n * (KK * KK);

    float4 a4[4][2];
    #pragma unroll
    for (int i = 0; i < 4; ++i) {
        const float* src = Om + base + (size_t)(r0 + i) * KK + c0;
        a4[i][0] = *(const float4*)(src);
        a4[i][1] = *(const float4*)(src + 4);
    }

    for (int g = 0; g < 32; ++g) {
        const int buf = g & 1;
        const int pgc = g >> 1;
        const int sub = g & 1;
        float* RB = rowblk + buf * 528;
        float* RS = rowstar + buf * 528;
        float* CP = cpan + buf * 512;

        if (rg == g) {
            #pragma unroll
            for (int p = 0; p < 4; ++p) {
                *(float4*)&RB[p * 132 + c0]     = a4[p][0];
                *(float4*)&RB[p * 132 + c0 + 4] = a4[p][1];
            }
        }
        if (cg == pgc) {
            if (sub == 0) {
                #pragma unroll
                for (int i = 0; i < 4; ++i)
                    *(float4*)&CP[(r0 + i) * 4] = a4[i][0];
            } else {
                #pragma unroll
                for (int i = 0; i < 4; ++i)
                    *(float4*)&CP[(r0 + i) * 4] = a4[i][1];
            }
        }
        __syncthreads();                                   // B1

        float4 p0 = *(const float4*)&RB[0 * 132 + 4 * g];
        float4 p1 = *(const float4*)&RB[1 * 132 + 4 * g];
        float4 p2 = *(const float4*)&RB[2 * 132 + 4 * g];
        float4 p3 = *(const float4*)&RB[3 * 132 + 4 * g];
        const float s0 = p0.x*p1.y - p1.x*p0.y;
        const float s1 = p0.x*p1.z - p1.x*p0.z;
        const float s2 = p0.x*p1.w - p1.x*p0.w;
        const float s3 = p0.y*p1.z - p1.y*p0.z;
        const float s4 = p0.y*p1.w - p1.y*p0.w;
        const float s5 = p0.z*p1.w - p1.z*p0.w;
        const float c5 = p2.z*p3.w - p3.z*p2.w;
        const float c4 = p2.y*p3.w - p3.y*p2.w;
        const float c3 = p2.y*p3.z - p3.y*p2.z;
        const float c2 = p2.x*p3.w - p3.x*p2.w;
        const float c1 = p2.x*p3.z - p3.x*p2.z;
        const float c0f = p2.x*p3.y - p3.x*p2.y;
        const float det = s0*c5 - s1*c4 + s2*c3 + s3*c2 - s4*c1 + s5*c0f;
        const float id  = 1.0f / det;

        {
            const int c = tid & 127;
            const float r0v = RB[0 * 132 + c];
            const float r1v = RB[1 * 132 + c];
            const float r2v = RB[2 * 132 + c];
            const float r3v = RB[3 * 132 + c];
            const int cl = c - 4 * g;
            const int pq = tid >> 7;
            if (pq == 0) {
                const float Pi0 = ( p1.y*c5 - p1.z*c4 + p1.w*c3) * id;
                const float Pi1 = (-p0.y*c5 + p0.z*c4 - p0.w*c3) * id;
                const float Pi2 = ( p3.y*s5 - p3.z*s4 + p3.w*s3) * id;
                const float Pi3 = (-p2.y*s5 + p2.z*s4 - p2.w*s3) * id;
                float v = Pi0*r0v + Pi1*r1v + Pi2*r2v + Pi3*r3v;
                if      (cl == 0) v += Pi0;
                else if (cl == 1) v += Pi1;
                else if (cl == 2) v += Pi2;
                else if (cl == 3) v += Pi3;
                RS[0 * 132 + c] = v;
            } else if (pq == 1) {
                const float Pi0 = (-p1.x*c5 + p1.z*c2 - p1.w*c1) * id;
                const float Pi1 = ( p0.x*c5 - p0.z*c2 + p0.w*c1) * id;
                const float Pi2 = (-p3.x*s5 + p3.z*s2 - p3.w*s1) * id;
                const float Pi3 = ( p2.x*s5 - p2.z*s2 + p2.w*s1) * id;
                float v = Pi0*r0v + Pi1*r1v + Pi2*r2v + Pi3*r3v;
                if      (cl == 0) v += Pi0;
                else if (cl == 1) v += Pi1;
                else if (cl == 2) v += Pi2;
                else if (cl == 3) v += Pi3;
                RS[1 * 132 + c] = v;
            } else if (pq == 2) {
                const float Pi0 = ( p1.x*c4 - p1.y*c2 + p1.w*c0f) * id;
                const float Pi1 = (-p0.x*c4 + p0.y*c2 - p0.w*c0f) * id;
                const float Pi2 = ( p3.x*s4 - p3.y*s2 + p3.w*s0) * id;
                const float Pi3 = (-p2.x*s4 + p2.y*s2 - p2.w*s0) * id;
                float v = Pi0*r0v + Pi1*r1v + Pi2*r2v + Pi3*r3v;
                if      (cl == 0) v += Pi0;
                else if (cl == 1) v += Pi1;
                else if (cl == 2) v += Pi2;
                else if (cl == 3) v += Pi3;
                RS[2 * 132 + c] = v;
            } else {
                const float Pi0 = (-p1.x*c3 + p1.y*c1 - p1.z*c0f) * id;
                const float Pi1 = ( p0.x*c3 - p0.y*c1 + p0.z*c0f) * id;
                const float Pi2 = (-p3.x*s3 + p3.y*s1 - p3.z*s0) * id;
                const float Pi3 = ( p2.x*s3 - p2.y*s1 + p2.z*s0) * id;
                float v = Pi0*r0v + Pi1*r1v + Pi2*r2v + Pi3*r3v;
                if      (cl == 0) v += Pi0;
                else if (cl == 1) v += Pi1;
                else if (cl == 2) v += Pi2;
                else if (cl == 3) v += Pi3;
                RS[3 * 132 + c] = v;
            }
        }
        __syncthreads();                                   // B2

        const bool piv_rg = (rg == g);
        #pragma unroll
        for (int h = 0; h < 2; ++h) {
            const int ch = c0 + h * 4;
            float4 rs0 = *(const float4*)&RS[0 * 132 + ch];
            float4 rs1 = *(const float4*)&RS[1 * 132 + ch];
            float4 rs2 = *(const float4*)&RS[2 * 132 + ch];
            float4 rs3 = *(const float4*)&RS[3 * 132 + ch];
            #pragma unroll
            for (int i = 0; i < 4; ++i) {
                float4 f = *(const float4*)&CP[(r0 + i) * 4];
                if (piv_rg) {
                    if (i == 0) f.x -= 1.0f;
                    else if (i == 1) f.y -= 1.0f;
                    else if (i == 2) f.z -= 1.0f;
                    else f.w -= 1.0f;
                }
                a4[i][h].x = fmaf(-f.x, rs0.x, fmaf(-f.y, rs1.x, fmaf(-f.z, rs2.x, fmaf(-f.w, rs3.x, a4[i][h].x))));
                a4[i][h].y = fmaf(-f.x, rs0.y, fmaf(-f.y, rs1.y, fmaf(-f.z, rs2.y, fmaf(-f.w, rs3.y, a4[i][h].y))));
                a4[i][h].z = fmaf(-f.x, rs0.z, fmaf(-f.y, rs1.z, fmaf(-f.z, rs2.z, fmaf(-f.w, rs3.z, a4[i][h].z))));
                a4[i][h].w = fmaf(-f.x, rs0.w, fmaf(-f.y, rs1.w, fmaf(-f.z, rs2.w, fmaf(-f.w, rs3.w, a4[i][h].w))));
            }
        }
        // no end barrier: LDS double-buffered by parity
    }

    #pragma unroll
    for (int i = 0; i < 4; ++i) {
        float* dst = Inv + base + (size_t)(r0 + i) * KK + c0;
        *(float4*)(dst)     = a4[i][0];
        *(float4*)(dst + 4) = a4[i][1];
    }
}

// ---------------------------------------------------------------------------
// FUSED heterogeneous kernel: even blocks run a GEMM tile (MFMA-bound),
// odd blocks run one matrix inverse (barrier/LDS-latency bound, MfmaUtil 0).
// Data-independent; co-resident blocks overlap MFMA and VALU/latency pipes
// (m114), hiding most of the invert cost under the GEMM.
// ---------------------------------------------------------------------------
__global__ __launch_bounds__(512) void gemm_invert_fused(
    const float* __restrict__ beta,
    const unsigned short* __restrict__ Sth,
    const unsigned short* __restrict__ Stl,
    float* __restrict__ W,
    const float* __restrict__ Om,
    float* __restrict__ Inv)
{
    __shared__ __align__(16) char smem[45056];
    const int b = blockIdx.x;
    if ((b & 1) == 0) {
        const int g = b >> 1;            // 0..1023
        gemm_body(beta, Sth, Stl, W, g & 127, g >> 7, threadIdx.x, smem);
    } else {
        const int n = b >> 1;            // 0..1023
        invert_body(Om, Inv, n, threadIdx.x, smem);
    }
}

// ---- standalone wrappers (tight-ws path) ----
__global__ __launch_bounds__(512) void gemm_kernel(
    const float* __restrict__ beta,
    const unsigned short* __restrict__ Sth,
    const unsigned short* __restrict__ Stl,
    float* __restrict__ W)
{
    __shared__ __align__(16) char smem[45056];
    gemm_body(beta, Sth, Stl, W, blockIdx.x, blockIdx.y, threadIdx.x, smem);
}

__global__ __launch_bounds__(512) void invert_kernel(
    const float* __restrict__ Om, float* __restrict__ Inv)
{
    __shared__ __align__(16) char smem[12544];
    invert_body(Om, Inv, blockIdx.x, threadIdx.x, smem);
}

// ---------------------------------------------------------------------------
extern "C" void kernel_launch(void* const* d_in, const int* in_sizes, int n_in,
                              void* d_out, int out_size, void* d_ws, size_t ws_size,
                              hipStream_t stream)
{
    const float* beta  = (const float*)d_in[0];
    const float* omega = (const float*)d_in[1];
    const float* Lp    = (const float*)d_in[2];
    const float* Lq    = (const float*)d_in[3];
    const float* obs   = (const float*)d_in[4];
    float* out = (float*)d_out;

    const size_t MATE = (size_t)NN * KK * KK;      // 16.8M elements (64 MB f32)

    if (ws_size >= 2 * MATE * sizeof(float)) {
        // [S f32 64MB][Sth 32MB][Stl 32MB]; after transpose S region is dead.
        // Fused kernel: Inv -> ws[0:64MB] (S region), W -> out.
        // NO overlap with live Sth/Stl (concurrency-safe, unlike R12 layout).
        float* S = (float*)d_ws;
        unsigned short* Sth = (unsigned short*)((char*)d_ws + MATE * sizeof(float));
        unsigned short* Stl = Sth + MATE;
        float* Inv  = (float*)d_ws;
        float* Wbuf = out;

        // 1. S_n = Omega_n^T Lq_n Omega_n
        sandwich_mfma<false><<<dim3(NN), dim3(512), 0, stream>>>(
            Lq, omega, S, nullptr, nullptr, nullptr, nullptr);
        // 2. split-transpose S -> Sth/Stl
        split_transpose_kernel<<<dim3(128, 8), dim3(256), 0, stream>>>(S, Sth, Stl);
        // 3. fused: W = beta_nd @ S  ||  Inv = omega^{-1}
        gemm_invert_fused<<<dim3(2048), dim3(512), 0, stream>>>(
            beta, Sth, Stl, Wbuf, omega, Inv);
        // 4. M = Inv^T W Inv + epilogue
        sandwich_mfma<true><<<dim3(NN), dim3(512), 0, stream>>>(
            Wbuf, Inv, out, Lp, Lq, obs, beta);
    } else {
        // tight path: sequential (Sth/Stl borrow d_out)
        float* S = (float*)d_ws;
        unsigned short* Sth = (unsigned short*)out;
        unsigned short* Stl = Sth + MATE;
        float* Wbuf = (float*)d_ws;
        float* Inv  = out;

        sandwich_mfma<false><<<dim3(NN), dim3(512), 0, stream>>>(
            Lq, omega, S, nullptr, nullptr, nullptr, nullptr);
        split_transpose_kernel<<<dim3(128, 8), dim3(256), 0, stream>>>(S, Sth, Stl);
        gemm_kernel<<<dim3(128, 8), dim3(512), 0, stream>>>(beta, Sth, Stl, Wbuf);
        invert_kernel<<<dim3(NN), dim3(512), 0, stream>>>(omega, Inv);
        sandwich_mfma<true><<<dim3(NN), dim3(512), 0, stream>>>(
            Wbuf, Inv, out, Lp, Lq, obs, beta);
    }
}

// Round 16
// 425.035 us; speedup vs baseline: 2.5470x; 2.5470x over previous
//
#include <hip/hip_runtime.h>

#define NN 1024
#define KK 128

typedef __attribute__((ext_vector_type(8))) short bf16x8;
typedef __attribute__((ext_vector_type(4))) float f32x4;
typedef __attribute__((ext_vector_type(8))) unsigned short u16x8;

__device__ __forceinline__ unsigned int bf16rne(float x) {
    unsigned int u = __float_as_uint(x);
    return (u + 0x7FFFu + ((u >> 16) & 1u)) >> 16;
}

__device__ __forceinline__ void split8(const float* xs, bf16x8& h8, bf16x8& l8) {
    #pragma unroll
    for (int j = 0; j < 8; ++j) {
        unsigned int hb = bf16rne(xs[j]);
        float hf = __uint_as_float(hb << 16);
        h8[j] = (short)hb;
        l8[j] = (short)bf16rne(xs[j] - hf);
    }
}

// ---------------------------------------------------------------------------
// MFMA sandwich, split-bf16, 512 threads / 8 waves (R12 form: pan staging).
// ---------------------------------------------------------------------------
template<bool FINAL>
__global__ __launch_bounds__(512) void sandwich_mfma(
    const float* __restrict__ A_, const float* __restrict__ B_,
    float* __restrict__ Out,
    const float* __restrict__ Lp, const float* __restrict__ Lq,
    const float* __restrict__ obs, const float* __restrict__ beta)
{
    __shared__ short lds_buf[69632];
    short* Bth = lds_buf;
    short* Btl = lds_buf + 17408;
    short* Tth = lds_buf + 34816;
    short* Ttl = lds_buf + 52224;
    float* pan = (float*)(lds_buf + 34816);
    __shared__ float wred[8];
    __shared__ float cs_sh;

    const int n    = blockIdx.x;
    const int tid  = threadIdx.x;
    const int lane = tid & 63;
    const int wid  = tid >> 6;
    const int wr   = wid >> 1;          // 0..3 row group (32 rows)
    const int wc   = wid & 1;           // 0..1 col group (64 cols)
    const int lm   = lane & 15;
    const int lk   = lane >> 4;
    const size_t base = (size_t)n * (KK * KK);

    if (FINAL) {
        float s = 0.f;
        for (int j = tid; j < NN; j += 512)
            if (j != n) s += beta[(size_t)j * NN + n];
        #pragma unroll
        for (int off = 32; off >= 1; off >>= 1) s += __shfl_down(s, off);
        if (lane == 0) wred[wid] = s;
        __syncthreads();
        if (tid == 0) {
            float t = 0.f;
            #pragma unroll
            for (int w = 0; w < 8; ++w) t += wred[w];
            cs_sh = t;
        }
    }

    // ---- stage Bt = B^T (hi/lo bf16) via two 64-col f32 panels ----
    #pragma unroll
    for (int cp = 0; cp < 2; ++cp) {
        #pragma unroll
        for (int it = 0; it < 4; ++it) {
            int gid = it * 512 + tid;
            int k   = gid >> 4;
            int c4  = (gid & 15) * 4;
            *(float4*)&pan[k * 66 + c4] =
                *(const float4*)(B_ + base + (size_t)k * KK + cp * 64 + c4);
        }
        __syncthreads();
        #pragma unroll
        for (int it = 0; it < 2; ++it) {
            int t  = it * 512 + tid;
            int c  = t >> 4;
            int ko = (t & 15) * 8;
            float xs[8];
            #pragma unroll
            for (int j = 0; j < 8; ++j) xs[j] = pan[(ko + j) * 66 + c];
            bf16x8 h8, l8;
            split8(xs, h8, l8);
            const int gc = cp * 64 + c;
            *(bf16x8*)&Bth[gc * 136 + ko] = h8;
            *(bf16x8*)&Btl[gc * 136 + ko] = l8;
        }
        __syncthreads();
    }

    // ================= stage 1: T = A @ B =================
    f32x4 acc[2][4];
    #pragma unroll
    for (int a = 0; a < 2; ++a)
        #pragma unroll
        for (int b = 0; b < 4; ++b) acc[a][b] = (f32x4){0.f, 0.f, 0.f, 0.f};

    #pragma unroll 1
    for (int ks = 0; ks < 4; ++ks) {
        const int k0 = ks * 32;
        bf16x8 afh[2], afl[2], bfh[4], bfl[4];
        #pragma unroll
        for (int rt = 0; rt < 2; ++rt) {
            const int r = wr * 32 + rt * 16 + lm;
            const float* ap = A_ + base + (size_t)r * KK + k0 + lk * 8;
            float4 x0 = *(const float4*)ap;
            float4 x1 = *(const float4*)(ap + 4);
            float xs[8] = {x0.x, x0.y, x0.z, x0.w, x1.x, x1.y, x1.z, x1.w};
            split8(xs, afh[rt], afl[rt]);
        }
        #pragma unroll
        for (int ct = 0; ct < 4; ++ct) {
            const int c = wc * 64 + ct * 16 + lm;
            bfh[ct] = *(const bf16x8*)&Bth[c * 136 + k0 + lk * 8];
            bfl[ct] = *(const bf16x8*)&Btl[c * 136 + k0 + lk * 8];
        }
        #pragma unroll
        for (int rt = 0; rt < 2; ++rt)
            #pragma unroll
            for (int ct = 0; ct < 4; ++ct) {
                acc[rt][ct] = __builtin_amdgcn_mfma_f32_16x16x32_bf16(
                    afh[rt], bfh[ct], acc[rt][ct], 0, 0, 0);
                acc[rt][ct] = __builtin_amdgcn_mfma_f32_16x16x32_bf16(
                    afh[rt], bfl[ct], acc[rt][ct], 0, 0, 0);
                acc[rt][ct] = __builtin_amdgcn_mfma_f32_16x16x32_bf16(
                    afl[rt], bfh[ct], acc[rt][ct], 0, 0, 0);
            }
    }

    // ---- T -> Tt[c][k] hi/lo ----
    #pragma unroll
    for (int rt = 0; rt < 2; ++rt)
        #pragma unroll
        for (int ct = 0; ct < 4; ++ct) {
            const int col  = wc * 64 + ct * 16 + lm;
            const int row0 = wr * 32 + rt * 16 + lk * 4;
            unsigned short h[4], l[4];
            #pragma unroll
            for (int j = 0; j < 4; ++j) {
                float x = acc[rt][ct][j];
                unsigned int hb = bf16rne(x);
                h[j] = (unsigned short)hb;
                l[j] = (unsigned short)bf16rne(x - __uint_as_float(hb << 16));
            }
            *(ushort4*)&Tth[col * 136 + row0] = make_ushort4(h[0], h[1], h[2], h[3]);
            *(ushort4*)&Ttl[col * 136 + row0] = make_ushort4(l[0], l[1], l[2], l[3]);
        }
    __syncthreads();

    // ================= stage 2: Out = B^T @ T =================
    f32x4 acc2[2][4];
    #pragma unroll
    for (int a = 0; a < 2; ++a)
        #pragma unroll
        for (int b = 0; b < 4; ++b) acc2[a][b] = (f32x4){0.f, 0.f, 0.f, 0.f};

    #pragma unroll 1
    for (int ks = 0; ks < 4; ++ks) {
        const int k0 = ks * 32;
        bf16x8 afh[2], afl[2], bfh[4], bfl[4];
        #pragma unroll
        for (int rt = 0; rt < 2; ++rt) {
            const int r = wr * 32 + rt * 16 + lm;
            afh[rt] = *(const bf16x8*)&Bth[r * 136 + k0 + lk * 8];
            afl[rt] = *(const bf16x8*)&Btl[r * 136 + k0 + lk * 8];
        }
        #pragma unroll
        for (int ct = 0; ct < 4; ++ct) {
            const int c = wc * 64 + ct * 16 + lm;
            bfh[ct] = *(const bf16x8*)&Tth[c * 136 + k0 + lk * 8];
            bfl[ct] = *(const bf16x8*)&Ttl[c * 136 + k0 + lk * 8];
        }
        #pragma unroll
        for (int rt = 0; rt < 2; ++rt)
            #pragma unroll
            for (int ct = 0; ct < 4; ++ct) {
                acc2[rt][ct] = __builtin_amdgcn_mfma_f32_16x16x32_bf16(
                    afh[rt], bfh[ct], acc2[rt][ct], 0, 0, 0);
                acc2[rt][ct] = __builtin_amdgcn_mfma_f32_16x16x32_bf16(
                    afh[rt], bfl[ct], acc2[rt][ct], 0, 0, 0);
                acc2[rt][ct] = __builtin_amdgcn_mfma_f32_16x16x32_bf16(
                    afl[rt], bfh[ct], acc2[rt][ct], 0, 0, 0);
            }
    }

    // ================= epilogue + store =================
    const float csv = FINAL ? cs_sh : 0.f;
    #pragma unroll
    for (int rt = 0; rt < 2; ++rt)
        #pragma unroll
        for (int ct = 0; ct < 4; ++ct) {
            const int col  = wc * 64 + ct * 16 + lm;
            const int row0 = wr * 32 + rt * 16 + lk * 4;
            #pragma unroll
            for (int j = 0; j < 4; ++j) {
                const int row = row0 + j;
                float o = acc2[rt][ct][j];
                if (FINAL) {
                    o += Lp[base + (size_t)row * KK + col]
                       + csv * Lq[base + (size_t)row * KK + col]
                       + obs[(size_t)row * KK + col];
                }
                Out[base + (size_t)row * KK + col] = o;
            }
        }
}

// ---------------------------------------------------------------------------
// Split-transpose: S (f32, [1024][16384]) -> Sth/Stl (bf16, [16384][1024]).
// ---------------------------------------------------------------------------
__global__ __launch_bounds__(256) void split_transpose_kernel(
    const float* __restrict__ S,
    unsigned short* __restrict__ Th, unsigned short* __restrict__ Tl)
{
    __shared__ float tile[128][132];
    const int tid = threadIdx.x;
    const int c0  = blockIdx.x * 128;
    const int k0  = blockIdx.y * 128;

    #pragma unroll
    for (int it = 0; it < 16; ++it) {
        int gid = it * 256 + tid;
        int kk  = gid >> 5;
        int c4  = (gid & 31) * 4;
        float4 v = *(const float4*)(S + (size_t)(k0 + kk) * 16384 + c0 + c4);
        *(float4*)&tile[kk][c4] = v;
    }
    __syncthreads();
    #pragma unroll
    for (int it = 0; it < 8; ++it) {
        int gid = it * 256 + tid;
        int c   = gid >> 4;
        int kc  = (gid & 15) * 8;
        u16x8 h, l;
        #pragma unroll
        for (int j = 0; j < 8; ++j) {
            float x = tile[kc + j][c];
            unsigned int hb = bf16rne(x);
            float hf = __uint_as_float(hb << 16);
            h[j] = (unsigned short)hb;
            l[j] = (unsigned short)bf16rne(x - hf);
        }
        size_t o = (size_t)(c0 + c) * 1024 + k0 + kc;
        *(u16x8*)(Th + o) = h;
        *(u16x8*)(Tl + o) = l;
    }
}

// ---------------------------------------------------------------------------
// beta pre-split: beta f32 [i][k] -> hi/lo bf16 [i][k], diagonal zeroed.
// ---------------------------------------------------------------------------
__global__ __launch_bounds__(256) void beta_split_kernel(
    const float* __restrict__ beta,
    unsigned short* __restrict__ Bh, unsigned short* __restrict__ Bl)
{
    const int gid = blockIdx.x * 256 + threadIdx.x;
    const int r   = gid >> 8;
    const int c4  = (gid & 255) * 4;
    float4 v = *(const float4*)(beta + (size_t)r * NN + c4);
    if (r == c4 + 0) v.x = 0.f;
    if (r == c4 + 1) v.y = 0.f;
    if (r == c4 + 2) v.z = 0.f;
    if (r == c4 + 3) v.w = 0.f;
    float xs[4] = {v.x, v.y, v.z, v.w};
    unsigned short hs[4], ls[4];
    #pragma unroll
    for (int j = 0; j < 4; ++j) {
        unsigned int hb = bf16rne(xs[j]);
        hs[j] = (unsigned short)hb;
        ls[j] = (unsigned short)bf16rne(xs[j] - __uint_as_float(hb << 16));
    }
    *(ushort4*)(Bh + (size_t)r * NN + c4) = make_ushort4(hs[0], hs[1], hs[2], hs[3]);
    *(ushort4*)(Bl + (size_t)r * NN + c4) = make_ushort4(ls[0], ls[1], ls[2], ls[3]);
}

// ---------------------------------------------------------------------------
// Big GEMM via MFMA, split-bf16 (R9/R12 version, 256 threads, stride 44).
// ---------------------------------------------------------------------------
template<bool PRESPLIT>
__global__ __launch_bounds__(256) void gemm_beta_mfma(
    const float* __restrict__ beta,
    const unsigned short* __restrict__ Bth_g,
    const unsigned short* __restrict__ Btl_g,
    const unsigned short* __restrict__ Sth,
    const unsigned short* __restrict__ Stl,
    float* __restrict__ W)
{
    __shared__ unsigned short Ah[128][44], Al[128][44];
    __shared__ unsigned short Bh[128][44], Bl[128][44];

    const int tid  = threadIdx.x;
    const int lane = tid & 63;
    const int wid  = tid >> 6;
    const int wr   = wid >> 1, wc = wid & 1;
    const int lm   = lane & 15;
    const int lk   = lane >> 4;
    const int i0   = blockIdx.y * 128;
    const int cb   = blockIdx.x * 128;

    f32x4 acc[4][4];
    #pragma unroll
    for (int a = 0; a < 4; ++a)
        #pragma unroll
        for (int b = 0; b < 4; ++b) acc[a][b] = (f32x4){0.f, 0.f, 0.f, 0.f};

    for (int k0 = 0; k0 < 1024; k0 += 32) {
        if (PRESPLIT) {
            #pragma unroll
            for (int it = 0; it < 2; ++it) {
                int gid = it * 256 + tid;
                int r   = gid >> 2;
                int kc  = (gid & 3) * 8;
                size_t o = (size_t)(i0 + r) * NN + k0 + kc;
                *(u16x8*)&Ah[r][kc] = *(const u16x8*)(Bth_g + o);
                *(u16x8*)&Al[r][kc] = *(const u16x8*)(Btl_g + o);
            }
        } else {
            #pragma unroll
            for (int it = 0; it < 4; ++it) {
                int gid = it * 256 + tid;
                int r   = gid >> 3;
                int c4  = (gid & 7) * 4;
                int gi  = i0 + r;
                float4 v = *(const float4*)(beta + (size_t)gi * NN + k0 + c4);
                if (gi == k0 + c4 + 0) v.x = 0.f;
                if (gi == k0 + c4 + 1) v.y = 0.f;
                if (gi == k0 + c4 + 2) v.z = 0.f;
                if (gi == k0 + c4 + 3) v.w = 0.f;
                float xs[4] = {v.x, v.y, v.z, v.w};
                unsigned short hs[4], ls[4];
                #pragma unroll
                for (int j = 0; j < 4; ++j) {
                    unsigned int hb = bf16rne(xs[j]);
                    hs[j] = (unsigned short)hb;
                    ls[j] = (unsigned short)bf16rne(xs[j] - __uint_as_float(hb << 16));
                }
                *(ushort4*)&Ah[r][c4] = make_ushort4(hs[0], hs[1], hs[2], hs[3]);
                *(ushort4*)&Al[r][c4] = make_ushort4(ls[0], ls[1], ls[2], ls[3]);
            }
        }
        #pragma unroll
        for (int it = 0; it < 2; ++it) {
            int gid = it * 256 + tid;
            int c   = gid >> 2;
            int kc  = (gid & 3) * 8;
            size_t o = (size_t)(cb + c) * 1024 + k0 + kc;
            *(u16x8*)&Bh[c][kc] = *(const u16x8*)(Sth + o);
            *(u16x8*)&Bl[c][kc] = *(const u16x8*)(Stl + o);
        }
        __syncthreads();

        bf16x8 afh[4], afl[4], bfh[4], bfl[4];
        #pragma unroll
        for (int rt = 0; rt < 4; ++rt) {
            const int r = wr * 64 + rt * 16 + lm;
            afh[rt] = *(const bf16x8*)&Ah[r][lk * 8];
            afl[rt] = *(const bf16x8*)&Al[r][lk * 8];
        }
        #pragma unroll
        for (int ct = 0; ct < 4; ++ct) {
            const int c = wc * 64 + ct * 16 + lm;
            bfh[ct] = *(const bf16x8*)&Bh[c][lk * 8];
            bfl[ct] = *(const bf16x8*)&Bl[c][lk * 8];
        }
        #pragma unroll
        for (int rt = 0; rt < 4; ++rt)
            #pragma unroll
            for (int ct = 0; ct < 4; ++ct) {
                acc[rt][ct] = __builtin_amdgcn_mfma_f32_16x16x32_bf16(
                    afh[rt], bfh[ct], acc[rt][ct], 0, 0, 0);
                acc[rt][ct] = __builtin_amdgcn_mfma_f32_16x16x32_bf16(
                    afh[rt], bfl[ct], acc[rt][ct], 0, 0, 0);
                acc[rt][ct] = __builtin_amdgcn_mfma_f32_16x16x32_bf16(
                    afl[rt], bfh[ct], acc[rt][ct], 0, 0, 0);
            }
        __syncthreads();
    }

    #pragma unroll
    for (int rt = 0; rt < 4; ++rt)
        #pragma unroll
        for (int ct = 0; ct < 4; ++ct) {
            const int col = cb + wc * 64 + ct * 16 + lm;
            #pragma unroll
            for (int j = 0; j < 4; ++j) {
                const int row = i0 + wr * 64 + rt * 16 + lk * 4 + j;
                W[(size_t)row * 16384 + col] = acc[rt][ct][j];
            }
        }
}

// ---------------------------------------------------------------------------
// Batched 128x128 inverse — BLOCKED Gauss-Jordan, NB=4, NO pivoting.
// R12 structure (512 threads, 4x8 tile/thread, VGPR ~52) with ONE layout fix:
// cpan row stride 4 -> 5 floats, scalar publish/read. The old [128][4] layout
// put owner writes at 16-dword stride (banks {0,16} only, 16-way conflict,
// 8.9M conflict cycles). Stride 5 (20 dwords, gcd(20,32)=4) spreads to
// <=4-way. FP values and fmaf order unchanged => bit-identical output
// (absmax canary: 1.879048e9).
// ---------------------------------------------------------------------------
__global__ __launch_bounds__(512) void invert_kernel(
    const float* __restrict__ Om, float* __restrict__ Inv)
{
    const int n   = blockIdx.x;
    const int tid = threadIdx.x;
    const int rg  = tid >> 4;        // 0..31: row group (4 rows)
    const int cg  = tid & 15;        // 0..15: col group (8 cols)
    const int r0  = rg * 4;
    const int c0  = cg * 8;
    const size_t base = (size_t)n * (KK * KK);

    float4 a4[4][2];
    #pragma unroll
    for (int i = 0; i < 4; ++i) {
        const float* src = Om + base + (size_t)(r0 + i) * KK + c0;
        a4[i][0] = *(const float4*)(src);
        a4[i][1] = *(const float4*)(src + 4);
    }

    __shared__ __align__(16) float rowblk[2][4][132];
    __shared__ __align__(16) float rowstar[2][4][132];
    __shared__ float cpan[2][128 * 5];          // stride-5: conflict fix

    for (int g = 0; g < 32; ++g) {
        const int buf = g & 1;
        const int pgc = g >> 1;
        const int sub = g & 1;

        if (rg == g) {
            #pragma unroll
            for (int p = 0; p < 4; ++p) {
                *(float4*)&rowblk[buf][p][c0]     = a4[p][0];
                *(float4*)&rowblk[buf][p][c0 + 4] = a4[p][1];
            }
        }
        if (cg == pgc) {
            if (sub == 0) {
                #pragma unroll
                for (int i = 0; i < 4; ++i) {
                    float* cp = &cpan[buf][(r0 + i) * 5];
                    cp[0] = a4[i][0].x; cp[1] = a4[i][0].y;
                    cp[2] = a4[i][0].z; cp[3] = a4[i][0].w;
                }
            } else {
                #pragma unroll
                for (int i = 0; i < 4; ++i) {
                    float* cp = &cpan[buf][(r0 + i) * 5];
                    cp[0] = a4[i][1].x; cp[1] = a4[i][1].y;
                    cp[2] = a4[i][1].z; cp[3] = a4[i][1].w;
                }
            }
        }
        __syncthreads();                                   // B1

        float4 p0 = *(const float4*)&rowblk[buf][0][4 * g];
        float4 p1 = *(const float4*)&rowblk[buf][1][4 * g];
        float4 p2 = *(const float4*)&rowblk[buf][2][4 * g];
        float4 p3 = *(const float4*)&rowblk[buf][3][4 * g];
        const float s0 = p0.x*p1.y - p1.x*p0.y;
        const float s1 = p0.x*p1.z - p1.x*p0.z;
        const float s2 = p0.x*p1.w - p1.x*p0.w;
        const float s3 = p0.y*p1.z - p1.y*p0.z;
        const float s4 = p0.y*p1.w - p1.y*p0.w;
        const float s5 = p0.z*p1.w - p1.z*p0.w;
        const float c5 = p2.z*p3.w - p3.z*p2.w;
        const float c4 = p2.y*p3.w - p3.y*p2.w;
        const float c3 = p2.y*p3.z - p3.y*p2.z;
        const float c2 = p2.x*p3.w - p3.x*p2.w;
        const float c1 = p2.x*p3.z - p3.x*p2.z;
        const float c0f = p2.x*p3.y - p3.x*p2.y;
        const float det = s0*c5 - s1*c4 + s2*c3 + s3*c2 - s4*c1 + s5*c0f;
        const float id  = 1.0f / det;

        {
            const int c = tid & 127;
            const float r0v = rowblk[buf][0][c];
            const float r1v = rowblk[buf][1][c];
            const float r2v = rowblk[buf][2][c];
            const float r3v = rowblk[buf][3][c];
            const int cl = c - 4 * g;
            const int pq = tid >> 7;
            if (pq == 0) {
                const float Pi0 = ( p1.y*c5 - p1.z*c4 + p1.w*c3) * id;
                const float Pi1 = (-p0.y*c5 + p0.z*c4 - p0.w*c3) * id;
                const float Pi2 = ( p3.y*s5 - p3.z*s4 + p3.w*s3) * id;
                const float Pi3 = (-p2.y*s5 + p2.z*s4 - p2.w*s3) * id;
                float v = Pi0*r0v + Pi1*r1v + Pi2*r2v + Pi3*r3v;
                if      (cl == 0) v += Pi0;
                else if (cl == 1) v += Pi1;
                else if (cl == 2) v += Pi2;
                else if (cl == 3) v += Pi3;
                rowstar[buf][0][c] = v;
            } else if (pq == 1) {
                const float Pi0 = (-p1.x*c5 + p1.z*c2 - p1.w*c1) * id;
                const float Pi1 = ( p0.x*c5 - p0.z*c2 + p0.w*c1) * id;
                const float Pi2 = (-p3.x*s5 + p3.z*s2 - p3.w*s1) * id;
                const float Pi3 = ( p2.x*s5 - p2.z*s2 + p2.w*s1) * id;
                float v = Pi0*r0v + Pi1*r1v + Pi2*r2v + Pi3*r3v;
                if      (cl == 0) v += Pi0;
                else if (cl == 1) v += Pi1;
                else if (cl == 2) v += Pi2;
                else if (cl == 3) v += Pi3;
                rowstar[buf][1][c] = v;
            } else if (pq == 2) {
                const float Pi0 = ( p1.x*c4 - p1.y*c2 + p1.w*c0f) * id;
                const float Pi1 = (-p0.x*c4 + p0.y*c2 - p0.w*c0f) * id;
                const float Pi2 = ( p3.x*s4 - p3.y*s2 + p3.w*s0) * id;
                const float Pi3 = (-p2.x*s4 + p2.y*s2 - p2.w*s0) * id;
                float v = Pi0*r0v + Pi1*r1v + Pi2*r2v + Pi3*r3v;
                if      (cl == 0) v += Pi0;
                else if (cl == 1) v += Pi1;
                else if (cl == 2) v += Pi2;
                else if (cl == 3) v += Pi3;
                rowstar[buf][2][c] = v;
            } else {
                const float Pi0 = (-p1.x*c3 + p1.y*c1 - p1.z*c0f) * id;
                const float Pi1 = ( p0.x*c3 - p0.y*c1 + p0.z*c0f) * id;
                const float Pi2 = (-p3.x*s3 + p3.y*s1 - p3.z*s0) * id;
                const float Pi3 = ( p2.x*s3 - p2.y*s1 + p2.z*s0) * id;
                float v = Pi0*r0v + Pi1*r1v + Pi2*r2v + Pi3*r3v;
                if      (cl == 0) v += Pi0;
                else if (cl == 1) v += Pi1;
                else if (cl == 2) v += Pi2;
                else if (cl == 3) v += Pi3;
                rowstar[buf][3][c] = v;
            }
        }
        __syncthreads();                                   // B2

        const bool piv_rg = (rg == g);
        #pragma unroll
        for (int h = 0; h < 2; ++h) {
            const int ch = c0 + h * 4;
            float4 rs0 = *(const float4*)&rowstar[buf][0][ch];
            float4 rs1 = *(const float4*)&rowstar[buf][1][ch];
            float4 rs2 = *(const float4*)&rowstar[buf][2][ch];
            float4 rs3 = *(const float4*)&rowstar[buf][3][ch];
            #pragma unroll
            for (int i = 0; i < 4; ++i) {
                const float* cp = &cpan[buf][(r0 + i) * 5];
                float4 f;
                f.x = cp[0]; f.y = cp[1]; f.z = cp[2]; f.w = cp[3];
                if (piv_rg) {
                    if (i == 0) f.x -= 1.0f;
                    else if (i == 1) f.y -= 1.0f;
                    else if (i == 2) f.z -= 1.0f;
                    else f.w -= 1.0f;
                }
                a4[i][h].x = fmaf(-f.x, rs0.x, fmaf(-f.y, rs1.x, fmaf(-f.z, rs2.x, fmaf(-f.w, rs3.x, a4[i][h].x))));
                a4[i][h].y = fmaf(-f.x, rs0.y, fmaf(-f.y, rs1.y, fmaf(-f.z, rs2.y, fmaf(-f.w, rs3.y, a4[i][h].y))));
                a4[i][h].z = fmaf(-f.x, rs0.z, fmaf(-f.y, rs1.z, fmaf(-f.z, rs2.z, fmaf(-f.w, rs3.z, a4[i][h].z))));
                a4[i][h].w = fmaf(-f.x, rs0.w, fmaf(-f.y, rs1.w, fmaf(-f.z, rs2.w, fmaf(-f.w, rs3.w, a4[i][h].w))));
            }
        }
        // no end barrier: LDS double-buffered by parity
    }

    #pragma unroll
    for (int i = 0; i < 4; ++i) {
        float* dst = Inv + base + (size_t)(r0 + i) * KK + c0;
        *(float4*)(dst)     = a4[i][0];
        *(float4*)(dst + 4) = a4[i][1];
    }
}

// ---------------------------------------------------------------------------
extern "C" void kernel_launch(void* const* d_in, const int* in_sizes, int n_in,
                              void* d_out, int out_size, void* d_ws, size_t ws_size,
                              hipStream_t stream)
{
    const float* beta  = (const float*)d_in[0];
    const float* omega = (const float*)d_in[1];
    const float* Lp    = (const float*)d_in[2];
    const float* Lq    = (const float*)d_in[3];
    const float* obs   = (const float*)d_in[4];
    float* out = (float*)d_out;

    const size_t MATE = (size_t)NN * KK * KK;      // 16.8M elements (64 MB f32)

    if (ws_size >= 2 * MATE * sizeof(float)) {
        // [S f32 64MB][Sth 32MB][Stl 32MB]; S dead after transpose ->
        // Bh/Bl/Inv reuse (Inv tail overlaps Sth which is dead after gemm;
        // stream order makes this safe).
        float* S = (float*)d_ws;
        unsigned short* Sth = (unsigned short*)((char*)d_ws + MATE * sizeof(float));
        unsigned short* Stl = Sth + MATE;
        unsigned short* Bh  = (unsigned short*)d_ws;
        unsigned short* Bl  = Bh + (size_t)NN * NN;
        float* Inv  = (float*)((char*)d_ws + 2 * (size_t)NN * NN * sizeof(unsigned short));
        float* Wbuf = out;

        sandwich_mfma<false><<<dim3(NN), dim3(512), 0, stream>>>(
            Lq, omega, S, nullptr, nullptr, nullptr, nullptr);
        split_transpose_kernel<<<dim3(128, 8), dim3(256), 0, stream>>>(S, Sth, Stl);
        beta_split_kernel<<<dim3(1024), dim3(256), 0, stream>>>(beta, Bh, Bl);
        gemm_beta_mfma<true><<<dim3(128, 8), dim3(256), 0, stream>>>(
            beta, Bh, Bl, Sth, Stl, Wbuf);
        invert_kernel<<<dim3(NN), dim3(512), 0, stream>>>(omega, Inv);
        sandwich_mfma<true><<<dim3(NN), dim3(512), 0, stream>>>(
            Wbuf, Inv, out, Lp, Lq, obs, beta);
    } else {
        float* S = (float*)d_ws;
        unsigned short* Sth = (unsigned short*)out;
        unsigned short* Stl = Sth + MATE;
        float* Wbuf = (float*)d_ws;
        float* Inv  = out;

        sandwich_mfma<false><<<dim3(NN), dim3(512), 0, stream>>>(
            Lq, omega, S, nullptr, nullptr, nullptr, nullptr);
        split_transpose_kernel<<<dim3(128, 8), dim3(256), 0, stream>>>(S, Sth, Stl);
        gemm_beta_mfma<false><<<dim3(128, 8), dim3(256), 0, stream>>>(
            beta, nullptr, nullptr, Sth, Stl, Wbuf);
        invert_kernel<<<dim3(NN), dim3(512), 0, stream>>>(omega, Inv);
        sandwich_mfma<true><<<dim3(NN), dim3(512), 0, stream>>>(
            Wbuf, Inv, out, Lp, Lq, obs, beta);
    }
}

// Round 17
// 410.772 us; speedup vs baseline: 2.6355x; 1.0347x over previous
//
#include <hip/hip_runtime.h>

#define NN 1024
#define KK 128

typedef __attribute__((ext_vector_type(8))) short bf16x8;
typedef __attribute__((ext_vector_type(4))) float f32x4;
typedef __attribute__((ext_vector_type(8))) unsigned short u16x8;

__device__ __forceinline__ unsigned int bf16rne(float x) {
    unsigned int u = __float_as_uint(x);
    return (u + 0x7FFFu + ((u >> 16) & 1u)) >> 16;
}

__device__ __forceinline__ void split8(const float* xs, bf16x8& h8, bf16x8& l8) {
    #pragma unroll
    for (int j = 0; j < 8; ++j) {
        unsigned int hb = bf16rne(xs[j]);
        float hf = __uint_as_float(hb << 16);
        h8[j] = (short)hb;
        l8[j] = (short)bf16rne(xs[j] - hf);
    }
}

// ---------------------------------------------------------------------------
// MFMA sandwich: Out_n = B_n^T (A_n B_n)  [+ epilogue for FINAL], split-bf16.
// 512 threads / 8 waves (R10 configuration — best measured total 409.7us).
// ---------------------------------------------------------------------------
template<bool FINAL>
__global__ __launch_bounds__(512) void sandwich_mfma(
    const float* __restrict__ A_, const float* __restrict__ B_,
    float* __restrict__ Out,
    const float* __restrict__ Lp, const float* __restrict__ Lq,
    const float* __restrict__ obs, const float* __restrict__ beta)
{
    __shared__ short lds_buf[69632];
    short* Bth = lds_buf;
    short* Btl = lds_buf + 17408;
    short* Tth = lds_buf + 34816;
    short* Ttl = lds_buf + 52224;
    float* pan = (float*)(lds_buf + 34816);
    __shared__ float wred[8];
    __shared__ float cs_sh;

    const int n    = blockIdx.x;
    const int tid  = threadIdx.x;
    const int lane = tid & 63;
    const int wid  = tid >> 6;          // 0..7
    const int wr   = wid >> 1;          // 0..3 row group (32 rows)
    const int wc   = wid & 1;           // 0..1 col group (64 cols)
    const int lm   = lane & 15;
    const int lk   = lane >> 4;
    const size_t base = (size_t)n * (KK * KK);

    if (FINAL) {
        float s = 0.f;
        for (int j = tid; j < NN; j += 512)
            if (j != n) s += beta[(size_t)j * NN + n];
        #pragma unroll
        for (int off = 32; off >= 1; off >>= 1) s += __shfl_down(s, off);
        if (lane == 0) wred[wid] = s;
        __syncthreads();
        if (tid == 0) {
            float t = 0.f;
            #pragma unroll
            for (int w = 0; w < 8; ++w) t += wred[w];
            cs_sh = t;
        }
    }

    // ---- stage Bt = B^T (hi/lo bf16) via two 64-col f32 panels ----
    #pragma unroll
    for (int cp = 0; cp < 2; ++cp) {
        #pragma unroll
        for (int it = 0; it < 4; ++it) {
            int gid = it * 512 + tid;       // 2048 float4 slots
            int k   = gid >> 4;
            int c4  = (gid & 15) * 4;
            *(float4*)&pan[k * 66 + c4] =
                *(const float4*)(B_ + base + (size_t)k * KK + cp * 64 + c4);
        }
        __syncthreads();
        #pragma unroll
        for (int it = 0; it < 2; ++it) {
            int t  = it * 512 + tid;        // 1024 tasks
            int c  = t >> 4;
            int ko = (t & 15) * 8;
            float xs[8];
            #pragma unroll
            for (int j = 0; j < 8; ++j) xs[j] = pan[(ko + j) * 66 + c];
            bf16x8 h8, l8;
            split8(xs, h8, l8);
            const int gc = cp * 64 + c;
            *(bf16x8*)&Bth[gc * 136 + ko] = h8;
            *(bf16x8*)&Btl[gc * 136 + ko] = l8;
        }
        __syncthreads();
    }

    // ================= stage 1: T = A @ B =================
    f32x4 acc[2][4];
    #pragma unroll
    for (int a = 0; a < 2; ++a)
        #pragma unroll
        for (int b = 0; b < 4; ++b) acc[a][b] = (f32x4){0.f, 0.f, 0.f, 0.f};

    #pragma unroll 1
    for (int ks = 0; ks < 4; ++ks) {
        const int k0 = ks * 32;
        bf16x8 afh[2], afl[2], bfh[4], bfl[4];
        #pragma unroll
        for (int rt = 0; rt < 2; ++rt) {
            const int r = wr * 32 + rt * 16 + lm;
            const float* ap = A_ + base + (size_t)r * KK + k0 + lk * 8;
            float4 x0 = *(const float4*)ap;
            float4 x1 = *(const float4*)(ap + 4);
            float xs[8] = {x0.x, x0.y, x0.z, x0.w, x1.x, x1.y, x1.z, x1.w};
            split8(xs, afh[rt], afl[rt]);
        }
        #pragma unroll
        for (int ct = 0; ct < 4; ++ct) {
            const int c = wc * 64 + ct * 16 + lm;
            bfh[ct] = *(const bf16x8*)&Bth[c * 136 + k0 + lk * 8];
            bfl[ct] = *(const bf16x8*)&Btl[c * 136 + k0 + lk * 8];
        }
        #pragma unroll
        for (int rt = 0; rt < 2; ++rt)
            #pragma unroll
            for (int ct = 0; ct < 4; ++ct) {
                acc[rt][ct] = __builtin_amdgcn_mfma_f32_16x16x32_bf16(
                    afh[rt], bfh[ct], acc[rt][ct], 0, 0, 0);
                acc[rt][ct] = __builtin_amdgcn_mfma_f32_16x16x32_bf16(
                    afh[rt], bfl[ct], acc[rt][ct], 0, 0, 0);
                acc[rt][ct] = __builtin_amdgcn_mfma_f32_16x16x32_bf16(
                    afl[rt], bfh[ct], acc[rt][ct], 0, 0, 0);
            }
    }

    // ---- T -> Tt[c][k] hi/lo ----
    #pragma unroll
    for (int rt = 0; rt < 2; ++rt)
        #pragma unroll
        for (int ct = 0; ct < 4; ++ct) {
            const int col  = wc * 64 + ct * 16 + lm;
            const int row0 = wr * 32 + rt * 16 + lk * 4;
            unsigned short h[4], l[4];
            #pragma unroll
            for (int j = 0; j < 4; ++j) {
                float x = acc[rt][ct][j];
                unsigned int hb = bf16rne(x);
                h[j] = (unsigned short)hb;
                l[j] = (unsigned short)bf16rne(x - __uint_as_float(hb << 16));
            }
            *(ushort4*)&Tth[col * 136 + row0] = make_ushort4(h[0], h[1], h[2], h[3]);
            *(ushort4*)&Ttl[col * 136 + row0] = make_ushort4(l[0], l[1], l[2], l[3]);
        }
    __syncthreads();

    // ================= stage 2: Out = B^T @ T =================
    f32x4 acc2[2][4];
    #pragma unroll
    for (int a = 0; a < 2; ++a)
        #pragma unroll
        for (int b = 0; b < 4; ++b) acc2[a][b] = (f32x4){0.f, 0.f, 0.f, 0.f};

    #pragma unroll 1
    for (int ks = 0; ks < 4; ++ks) {
        const int k0 = ks * 32;
        bf16x8 afh[2], afl[2], bfh[4], bfl[4];
        #pragma unroll
        for (int rt = 0; rt < 2; ++rt) {
            const int r = wr * 32 + rt * 16 + lm;
            afh[rt] = *(const bf16x8*)&Bth[r * 136 + k0 + lk * 8];
            afl[rt] = *(const bf16x8*)&Btl[r * 136 + k0 + lk * 8];
        }
        #pragma unroll
        for (int ct = 0; ct < 4; ++ct) {
            const int c = wc * 64 + ct * 16 + lm;
            bfh[ct] = *(const bf16x8*)&Tth[c * 136 + k0 + lk * 8];
            bfl[ct] = *(const bf16x8*)&Ttl[c * 136 + k0 + lk * 8];
        }
        #pragma unroll
        for (int rt = 0; rt < 2; ++rt)
            #pragma unroll
            for (int ct = 0; ct < 4; ++ct) {
                acc2[rt][ct] = __builtin_amdgcn_mfma_f32_16x16x32_bf16(
                    afh[rt], bfh[ct], acc2[rt][ct], 0, 0, 0);
                acc2[rt][ct] = __builtin_amdgcn_mfma_f32_16x16x32_bf16(
                    afh[rt], bfl[ct], acc2[rt][ct], 0, 0, 0);
                acc2[rt][ct] = __builtin_amdgcn_mfma_f32_16x16x32_bf16(
                    afl[rt], bfh[ct], acc2[rt][ct], 0, 0, 0);
            }
    }

    // ================= epilogue + store =================
    const float csv = FINAL ? cs_sh : 0.f;
    #pragma unroll
    for (int rt = 0; rt < 2; ++rt)
        #pragma unroll
        for (int ct = 0; ct < 4; ++ct) {
            const int col  = wc * 64 + ct * 16 + lm;
            const int row0 = wr * 32 + rt * 16 + lk * 4;
            #pragma unroll
            for (int j = 0; j < 4; ++j) {
                const int row = row0 + j;
                float o = acc2[rt][ct][j];
                if (FINAL) {
                    o += Lp[base + (size_t)row * KK + col]
                       + csv * Lq[base + (size_t)row * KK + col]
                       + obs[(size_t)row * KK + col];
                }
                Out[base + (size_t)row * KK + col] = o;
            }
        }
}

// ---------------------------------------------------------------------------
// Split-transpose: S (f32, [1024][16384]) -> Sth/Stl (bf16, [16384][1024]).
// ---------------------------------------------------------------------------
__global__ __launch_bounds__(256) void split_transpose_kernel(
    const float* __restrict__ S,
    unsigned short* __restrict__ Th, unsigned short* __restrict__ Tl)
{
    __shared__ float tile[128][132];
    const int tid = threadIdx.x;
    const int c0  = blockIdx.x * 128;
    const int k0  = blockIdx.y * 128;

    #pragma unroll
    for (int it = 0; it < 16; ++it) {
        int gid = it * 256 + tid;
        int kk  = gid >> 5;
        int c4  = (gid & 31) * 4;
        float4 v = *(const float4*)(S + (size_t)(k0 + kk) * 16384 + c0 + c4);
        *(float4*)&tile[kk][c4] = v;
    }
    __syncthreads();
    #pragma unroll
    for (int it = 0; it < 8; ++it) {
        int gid = it * 256 + tid;
        int c   = gid >> 4;
        int kc  = (gid & 15) * 8;
        u16x8 h, l;
        #pragma unroll
        for (int j = 0; j < 8; ++j) {
            float x = tile[kc + j][c];
            unsigned int hb = bf16rne(x);
            float hf = __uint_as_float(hb << 16);
            h[j] = (unsigned short)hb;
            l[j] = (unsigned short)bf16rne(x - hf);
        }
        size_t o = (size_t)(c0 + c) * 1024 + k0 + kc;
        *(u16x8*)(Th + o) = h;
        *(u16x8*)(Tl + o) = l;
    }
}

// ---------------------------------------------------------------------------
// beta pre-split: beta f32 [i][k] -> hi/lo bf16 [i][k], diagonal zeroed.
// ---------------------------------------------------------------------------
__global__ __launch_bounds__(256) void beta_split_kernel(
    const float* __restrict__ beta,
    unsigned short* __restrict__ Bh, unsigned short* __restrict__ Bl)
{
    const int gid = blockIdx.x * 256 + threadIdx.x;
    const int r   = gid >> 8;
    const int c4  = (gid & 255) * 4;
    float4 v = *(const float4*)(beta + (size_t)r * NN + c4);
    if (r == c4 + 0) v.x = 0.f;
    if (r == c4 + 1) v.y = 0.f;
    if (r == c4 + 2) v.z = 0.f;
    if (r == c4 + 3) v.w = 0.f;
    float xs[4] = {v.x, v.y, v.z, v.w};
    unsigned short hs[4], ls[4];
    #pragma unroll
    for (int j = 0; j < 4; ++j) {
        unsigned int hb = bf16rne(xs[j]);
        hs[j] = (unsigned short)hb;
        ls[j] = (unsigned short)bf16rne(xs[j] - __uint_as_float(hb << 16));
    }
    *(ushort4*)(Bh + (size_t)r * NN + c4) = make_ushort4(hs[0], hs[1], hs[2], hs[3]);
    *(ushort4*)(Bl + (size_t)r * NN + c4) = make_ushort4(ls[0], ls[1], ls[2], ls[3]);
}

// ---------------------------------------------------------------------------
// Big GEMM via MFMA, split-bf16 (R9/R10 version, 256 threads, stride 44).
// ---------------------------------------------------------------------------
template<bool PRESPLIT>
__global__ __launch_bounds__(256) void gemm_beta_mfma(
    const float* __restrict__ beta,
    const unsigned short* __restrict__ Bth_g,
    const unsigned short* __restrict__ Btl_g,
    const unsigned short* __restrict__ Sth,
    const unsigned short* __restrict__ Stl,
    float* __restrict__ W)
{
    __shared__ unsigned short Ah[128][44], Al[128][44];
    __shared__ unsigned short Bh[128][44], Bl[128][44];

    const int tid  = threadIdx.x;
    const int lane = tid & 63;
    const int wid  = tid >> 6;
    const int wr   = wid >> 1, wc = wid & 1;
    const int lm   = lane & 15;
    const int lk   = lane >> 4;
    const int i0   = blockIdx.y * 128;
    const int cb   = blockIdx.x * 128;

    f32x4 acc[4][4];
    #pragma unroll
    for (int a = 0; a < 4; ++a)
        #pragma unroll
        for (int b = 0; b < 4; ++b) acc[a][b] = (f32x4){0.f, 0.f, 0.f, 0.f};

    for (int k0 = 0; k0 < 1024; k0 += 32) {
        if (PRESPLIT) {
            #pragma unroll
            for (int it = 0; it < 2; ++it) {
                int gid = it * 256 + tid;
                int r   = gid >> 2;
                int kc  = (gid & 3) * 8;
                size_t o = (size_t)(i0 + r) * NN + k0 + kc;
                *(u16x8*)&Ah[r][kc] = *(const u16x8*)(Bth_g + o);
                *(u16x8*)&Al[r][kc] = *(const u16x8*)(Btl_g + o);
            }
        } else {
            #pragma unroll
            for (int it = 0; it < 4; ++it) {
                int gid = it * 256 + tid;
                int r   = gid >> 3;
                int c4  = (gid & 7) * 4;
                int gi  = i0 + r;
                float4 v = *(const float4*)(beta + (size_t)gi * NN + k0 + c4);
                if (gi == k0 + c4 + 0) v.x = 0.f;
                if (gi == k0 + c4 + 1) v.y = 0.f;
                if (gi == k0 + c4 + 2) v.z = 0.f;
                if (gi == k0 + c4 + 3) v.w = 0.f;
                float xs[4] = {v.x, v.y, v.z, v.w};
                unsigned short hs[4], ls[4];
                #pragma unroll
                for (int j = 0; j < 4; ++j) {
                    unsigned int hb = bf16rne(xs[j]);
                    hs[j] = (unsigned short)hb;
                    ls[j] = (unsigned short)bf16rne(xs[j] - __uint_as_float(hb << 16));
                }
                *(ushort4*)&Ah[r][c4] = make_ushort4(hs[0], hs[1], hs[2], hs[3]);
                *(ushort4*)&Al[r][c4] = make_ushort4(ls[0], ls[1], ls[2], ls[3]);
            }
        }
        #pragma unroll
        for (int it = 0; it < 2; ++it) {
            int gid = it * 256 + tid;
            int c   = gid >> 2;
            int kc  = (gid & 3) * 8;
            size_t o = (size_t)(cb + c) * 1024 + k0 + kc;
            *(u16x8*)&Bh[c][kc] = *(const u16x8*)(Sth + o);
            *(u16x8*)&Bl[c][kc] = *(const u16x8*)(Stl + o);
        }
        __syncthreads();

        bf16x8 afh[4], afl[4], bfh[4], bfl[4];
        #pragma unroll
        for (int rt = 0; rt < 4; ++rt) {
            const int r = wr * 64 + rt * 16 + lm;
            afh[rt] = *(const bf16x8*)&Ah[r][lk * 8];
            afl[rt] = *(const bf16x8*)&Al[r][lk * 8];
        }
        #pragma unroll
        for (int ct = 0; ct < 4; ++ct) {
            const int c = wc * 64 + ct * 16 + lm;
            bfh[ct] = *(const bf16x8*)&Bh[c][lk * 8];
            bfl[ct] = *(const bf16x8*)&Bl[c][lk * 8];
        }
        #pragma unroll
        for (int rt = 0; rt < 4; ++rt)
            #pragma unroll
            for (int ct = 0; ct < 4; ++ct) {
                acc[rt][ct] = __builtin_amdgcn_mfma_f32_16x16x32_bf16(
                    afh[rt], bfh[ct], acc[rt][ct], 0, 0, 0);
                acc[rt][ct] = __builtin_amdgcn_mfma_f32_16x16x32_bf16(
                    afh[rt], bfl[ct], acc[rt][ct], 0, 0, 0);
                acc[rt][ct] = __builtin_amdgcn_mfma_f32_16x16x32_bf16(
                    afl[rt], bfh[ct], acc[rt][ct], 0, 0, 0);
            }
        __syncthreads();
    }

    #pragma unroll
    for (int rt = 0; rt < 4; ++rt)
        #pragma unroll
        for (int ct = 0; ct < 4; ++ct) {
            const int col = cb + wc * 64 + ct * 16 + lm;
            #pragma unroll
            for (int j = 0; j < 4; ++j) {
                const int row = i0 + wr * 64 + rt * 16 + lk * 4 + j;
                W[(size_t)row * 16384 + col] = acc[rt][ct][j];
            }
        }
}

// ---------------------------------------------------------------------------
// Batched 128x128 inverse — BLOCKED Gauss-Jordan, NB=4, NO pivoting.
// R10 configuration: 256 threads, 8x8 tile/thread (VGPR 68) — the best
// measured variant (131.9us; the 4x8@512 forms measured 138-143us).
// ---------------------------------------------------------------------------
__global__ __launch_bounds__(256) void invert_kernel(
    const float* __restrict__ Om, float* __restrict__ Inv)
{
    const int n   = blockIdx.x;
    const int tid = threadIdx.x;
    const int rg  = tid >> 4;
    const int cg  = tid & 15;
    const int r0  = rg * 8;
    const int c0  = cg * 8;
    const size_t base = (size_t)n * (KK * KK);

    float4 a4[8][2];
    #pragma unroll
    for (int i = 0; i < 8; ++i) {
        const float* src = Om + base + (size_t)(r0 + i) * KK + c0;
        a4[i][0] = *(const float4*)(src);
        a4[i][1] = *(const float4*)(src + 4);
    }

    __shared__ __align__(16) float rowblk[2][4][132];
    __shared__ __align__(16) float rowstar[2][4][132];
    __shared__ __align__(16) float cpan[2][128][4];

    for (int g = 0; g < 32; ++g) {
        const int buf = g & 1;
        const int pg  = g >> 1;
        const int sub = g & 1;

        if (rg == pg) {
            if (sub == 0) {
                #pragma unroll
                for (int p = 0; p < 4; ++p) {
                    *(float4*)&rowblk[buf][p][c0]     = a4[p][0];
                    *(float4*)&rowblk[buf][p][c0 + 4] = a4[p][1];
                }
            } else {
                #pragma unroll
                for (int p = 0; p < 4; ++p) {
                    *(float4*)&rowblk[buf][p][c0]     = a4[4 + p][0];
                    *(float4*)&rowblk[buf][p][c0 + 4] = a4[4 + p][1];
                }
            }
        }
        if (cg == pg) {
            if (sub == 0) {
                #pragma unroll
                for (int i = 0; i < 8; ++i)
                    *(float4*)&cpan[buf][r0 + i][0] = a4[i][0];
            } else {
                #pragma unroll
                for (int i = 0; i < 8; ++i)
                    *(float4*)&cpan[buf][r0 + i][0] = a4[i][1];
            }
        }
        __syncthreads();

        float4 p0 = *(const float4*)&rowblk[buf][0][4 * g];
        float4 p1 = *(const float4*)&rowblk[buf][1][4 * g];
        float4 p2 = *(const float4*)&rowblk[buf][2][4 * g];
        float4 p3 = *(const float4*)&rowblk[buf][3][4 * g];
        const float s0 = p0.x*p1.y - p1.x*p0.y;
        const float s1 = p0.x*p1.z - p1.x*p0.z;
        const float s2 = p0.x*p1.w - p1.x*p0.w;
        const float s3 = p0.y*p1.z - p1.y*p0.z;
        const float s4 = p0.y*p1.w - p1.y*p0.w;
        const float s5 = p0.z*p1.w - p1.z*p0.w;
        const float c5 = p2.z*p3.w - p3.z*p2.w;
        const float c4 = p2.y*p3.w - p3.y*p2.w;
        const float c3 = p2.y*p3.z - p3.y*p2.z;
        const float c2 = p2.x*p3.w - p3.x*p2.w;
        const float c1 = p2.x*p3.z - p3.x*p2.z;
        const float c0f = p2.x*p3.y - p3.x*p2.y;
        const float det = s0*c5 - s1*c4 + s2*c3 + s3*c2 - s4*c1 + s5*c0f;
        const float id  = 1.0f / det;
        const float Pi00 = ( p1.y*c5 - p1.z*c4 + p1.w*c3) * id;
        const float Pi01 = (-p0.y*c5 + p0.z*c4 - p0.w*c3) * id;
        const float Pi02 = ( p3.y*s5 - p3.z*s4 + p3.w*s3) * id;
        const float Pi03 = (-p2.y*s5 + p2.z*s4 - p2.w*s3) * id;
        const float Pi10 = (-p1.x*c5 + p1.z*c2 - p1.w*c1) * id;
        const float Pi11 = ( p0.x*c5 - p0.z*c2 + p0.w*c1) * id;
        const float Pi12 = (-p3.x*s5 + p3.z*s2 - p3.w*s1) * id;
        const float Pi13 = ( p2.x*s5 - p2.z*s2 + p2.w*s1) * id;
        const float Pi20 = ( p1.x*c4 - p1.y*c2 + p1.w*c0f) * id;
        const float Pi21 = (-p0.x*c4 + p0.y*c2 - p0.w*c0f) * id;
        const float Pi22 = ( p3.x*s4 - p3.y*s2 + p3.w*s0) * id;
        const float Pi23 = (-p2.x*s4 + p2.y*s2 - p2.w*s0) * id;
        const float Pi30 = (-p1.x*c3 + p1.y*c1 - p1.z*c0f) * id;
        const float Pi31 = ( p0.x*c3 - p0.y*c1 + p0.z*c0f) * id;
        const float Pi32 = (-p3.x*s3 + p3.y*s1 - p3.z*s0) * id;
        const float Pi33 = ( p2.x*s3 - p2.y*s1 + p2.z*s0) * id;

        {
            const int c = tid & 127;
            const float r0v = rowblk[buf][0][c];
            const float r1v = rowblk[buf][1][c];
            const float r2v = rowblk[buf][2][c];
            const float r3v = rowblk[buf][3][c];
            const int cl = c - 4 * g;
            if (tid < 128) {
                float v0 = Pi00*r0v + Pi01*r1v + Pi02*r2v + Pi03*r3v;
                float v1 = Pi10*r0v + Pi11*r1v + Pi12*r2v + Pi13*r3v;
                if      (cl == 0) { v0 += Pi00; v1 += Pi10; }
                else if (cl == 1) { v0 += Pi01; v1 += Pi11; }
                else if (cl == 2) { v0 += Pi02; v1 += Pi12; }
                else if (cl == 3) { v0 += Pi03; v1 += Pi13; }
                rowstar[buf][0][c] = v0;
                rowstar[buf][1][c] = v1;
            } else {
                float v2 = Pi20*r0v + Pi21*r1v + Pi22*r2v + Pi23*r3v;
                float v3 = Pi30*r0v + Pi31*r1v + Pi32*r2v + Pi33*r3v;
                if      (cl == 0) { v2 += Pi20; v3 += Pi30; }
                else if (cl == 1) { v2 += Pi21; v3 += Pi31; }
                else if (cl == 2) { v2 += Pi22; v3 += Pi32; }
                else if (cl == 3) { v2 += Pi23; v3 += Pi33; }
                rowstar[buf][2][c] = v2;
                rowstar[buf][3][c] = v3;
            }
        }
        __syncthreads();

        float4 rs0a = *(const float4*)&rowstar[buf][0][c0];
        float4 rs0b = *(const float4*)&rowstar[buf][0][c0 + 4];
        float4 rs1a = *(const float4*)&rowstar[buf][1][c0];
        float4 rs1b = *(const float4*)&rowstar[buf][1][c0 + 4];
        float4 rs2a = *(const float4*)&rowstar[buf][2][c0];
        float4 rs2b = *(const float4*)&rowstar[buf][2][c0 + 4];
        float4 rs3a = *(const float4*)&rowstar[buf][3][c0];
        float4 rs3b = *(const float4*)&rowstar[buf][3][c0 + 4];

        const bool piv_rg = (rg == pg);
        #pragma unroll
        for (int i = 0; i < 8; ++i) {
            float4 f = *(const float4*)&cpan[buf][r0 + i][0];
            if (piv_rg) {
                if (sub == 0) {
                    if (i == 0) f.x -= 1.0f;
                    if (i == 1) f.y -= 1.0f;
                    if (i == 2) f.z -= 1.0f;
                    if (i == 3) f.w -= 1.0f;
                } else {
                    if (i == 4) f.x -= 1.0f;
                    if (i == 5) f.y -= 1.0f;
                    if (i == 6) f.z -= 1.0f;
                    if (i == 7) f.w -= 1.0f;
                }
            }
            a4[i][0].x = fmaf(-f.x, rs0a.x, fmaf(-f.y, rs1a.x, fmaf(-f.z, rs2a.x, fmaf(-f.w, rs3a.x, a4[i][0].x))));
            a4[i][0].y = fmaf(-f.x, rs0a.y, fmaf(-f.y, rs1a.y, fmaf(-f.z, rs2a.y, fmaf(-f.w, rs3a.y, a4[i][0].y))));
            a4[i][0].z = fmaf(-f.x, rs0a.z, fmaf(-f.y, rs1a.z, fmaf(-f.z, rs2a.z, fmaf(-f.w, rs3a.z, a4[i][0].z))));
            a4[i][0].w = fmaf(-f.x, rs0a.w, fmaf(-f.y, rs1a.w, fmaf(-f.z, rs2a.w, fmaf(-f.w, rs3a.w, a4[i][0].w))));
            a4[i][1].x = fmaf(-f.x, rs0b.x, fmaf(-f.y, rs1b.x, fmaf(-f.z, rs2b.x, fmaf(-f.w, rs3b.x, a4[i][1].x))));
            a4[i][1].y = fmaf(-f.x, rs0b.y, fmaf(-f.y, rs1b.y, fmaf(-f.z, rs2b.y, fmaf(-f.w, rs3b.y, a4[i][1].y))));
            a4[i][1].z = fmaf(-f.x, rs0b.z, fmaf(-f.y, rs1b.z, fmaf(-f.z, rs2b.z, fmaf(-f.w, rs3b.z, a4[i][1].z))));
            a4[i][1].w = fmaf(-f.x, rs0b.w, fmaf(-f.y, rs1b.w, fmaf(-f.z, rs2b.w, fmaf(-f.w, rs3b.w, a4[i][1].w))));
        }
    }

    #pragma unroll
    for (int i = 0; i < 8; ++i) {
        float* dst = Inv + base + (size_t)(r0 + i) * KK + c0;
        *(float4*)(dst)     = a4[i][0];
        *(float4*)(dst + 4) = a4[i][1];
    }
}

// ---------------------------------------------------------------------------
extern "C" void kernel_launch(void* const* d_in, const int* in_sizes, int n_in,
                              void* d_out, int out_size, void* d_ws, size_t ws_size,
                              hipStream_t stream)
{
    const float* beta  = (const float*)d_in[0];
    const float* omega = (const float*)d_in[1];
    const float* Lp    = (const float*)d_in[2];
    const float* Lq    = (const float*)d_in[3];
    const float* obs   = (const float*)d_in[4];
    float* out = (float*)d_out;

    const size_t MATE = (size_t)NN * KK * KK;      // 16.8M elements (64 MB f32)

    if (ws_size >= 2 * MATE * sizeof(float)) {
        float* S = (float*)d_ws;
        unsigned short* Sth = (unsigned short*)((char*)d_ws + MATE * sizeof(float));
        unsigned short* Stl = Sth + MATE;
        unsigned short* Bh  = (unsigned short*)d_ws;
        unsigned short* Bl  = Bh + (size_t)NN * NN;
        float* Inv  = (float*)((char*)d_ws + 2 * (size_t)NN * NN * sizeof(unsigned short));
        float* Wbuf = out;

        sandwich_mfma<false><<<dim3(NN), dim3(512), 0, stream>>>(
            Lq, omega, S, nullptr, nullptr, nullptr, nullptr);
        split_transpose_kernel<<<dim3(128, 8), dim3(256), 0, stream>>>(S, Sth, Stl);
        beta_split_kernel<<<dim3(1024), dim3(256), 0, stream>>>(beta, Bh, Bl);
        gemm_beta_mfma<true><<<dim3(128, 8), dim3(256), 0, stream>>>(
            beta, Bh, Bl, Sth, Stl, Wbuf);
        invert_kernel<<<dim3(NN), dim3(256), 0, stream>>>(omega, Inv);
        sandwich_mfma<true><<<dim3(NN), dim3(512), 0, stream>>>(
            Wbuf, Inv, out, Lp, Lq, obs, beta);
    } else {
        float* S = (float*)d_ws;
        unsigned short* Sth = (unsigned short*)out;
        unsigned short* Stl = Sth + MATE;
        float* Wbuf = (float*)d_ws;
        float* Inv  = out;

        sandwich_mfma<false><<<dim3(NN), dim3(512), 0, stream>>>(
            Lq, omega, S, nullptr, nullptr, nullptr, nullptr);
        split_transpose_kernel<<<dim3(128, 8), dim3(256), 0, stream>>>(S, Sth, Stl);
        gemm_beta_mfma<false><<<dim3(128, 8), dim3(256), 0, stream>>>(
            beta, nullptr, nullptr, Sth, Stl, Wbuf);
        invert_kernel<<<dim3(NN), dim3(256), 0, stream>>>(omega, Inv);
        sandwich_mfma<true><<<dim3(NN), dim3(512), 0, stream>>>(
            Wbuf, Inv, out, Lp, Lq, obs, beta);
    }
}